// Round 9
// baseline (371.372 us; speedup 1.0000x reference)
//
#include <hip/hip_runtime.h>
#include <hip/hip_bf16.h>

typedef __attribute__((ext_vector_type(8))) short short8;
typedef __attribute__((ext_vector_type(4))) float f32x4;

// ws layout: xbf (bf16 s_feats) at 0, 6,400,000 B; wfrag (fragment-major W) at
// 6,400,000, 131,072 B. wfrag: fragment f = (dt*2+kh)*16+jj holds, at lane l,
// elems W[pc = (kh*16+jj)*32 + 8*(l>>4) + e][d = dt*16 + (l&15)] at f*512+l*8+e.
#define WT_BYTE_OFF 6400000

// LDS layout (bytes) -- round-5 structure, unchanged:
//   wtd:  [0, 33024) = 16 queries x QSTRIDE(2064); wave w owns rows 2w,2w+1
//   x:    wave w's x^T tile [c-slot=64][k-swizzled], 4096 B, aliases slice head.
//         slot(c) = c ^ ((c>>5)&1) (32-bank write spread, 2 lanes/bank free)
//   nn:   [33024, 33088) 16 ints
//   pos:  [33088, +8*768) per-wave SoA xy float2[64] + z float[64]; DS-FIFO
//   red:  [33088, 37184) phase-4 partials -- aliases pos ACROSS barriers;
//         persistent loop adds a 3rd barrier so pos(t+1) never races red(t).
#define QSTRIDE   2064
#define XSLICE    4128
#define LDS_NN    33024
#define LDS_POS   33088
#define POSSTRIDE 768
#define LDS_RED   33088
#define LDS_TOT   (33088 + 8*768)

#define NTILES    3125
#define PGRID     1024   // 4 blocks/CU x 256 CU: fully resident, grid-stride

__device__ inline unsigned short f2bf(float x) {           // RNE, pre-kernel
    unsigned int u = __float_as_uint(x);
    unsigned int r = (u + 0x7FFFu + ((u >> 16) & 1u)) >> 16;
    return (unsigned short)r;
}

__device__ inline unsigned short f2bf_fast(float x) {      // native RNE convert
    __hip_bfloat16 b = __float2bfloat16(x);
    return *reinterpret_cast<unsigned short*>(&b);
}

__global__ void kpconv_pre(const float* __restrict__ s_feats,
                           const float* __restrict__ weights,
                           unsigned short* __restrict__ xbf,
                           unsigned short* __restrict__ wfrag) {
    int t = blockIdx.x * 256 + threadIdx.x;
    if (t < 800000) {                       // 3.2M elems / 4
        int i = t * 4;
        float4 v = *(const float4*)(s_feats + i);
        ushort4 o;
        o.x = f2bf(v.x); o.y = f2bf(v.y); o.z = f2bf(v.z); o.w = f2bf(v.w);
        *(ushort4*)(xbf + i) = o;
    } else {
        int tw = t - 800000;
        if (tw < 8192) {                    // 128 frags x 64 lanes, 16 B each
            const int f = tw >> 6, l = tw & 63;
            const int m = l & 15, h = l >> 4;
            const int dt = f >> 5, kh = (f >> 4) & 1, jj = f & 15;
            const int d = dt * 16 + m;
            const int pcb = (kh * 16 + jj) * 32 + 8 * h;
            ushort4 o0, o1;
            unsigned short* op0 = (unsigned short*)&o0;
            unsigned short* op1 = (unsigned short*)&o1;
            #pragma unroll
            for (int e = 0; e < 8; ++e) {
                const int pc = pcb + e;
                const int p = pc & 15, c = pc >> 4;
                const float wv = (p < 15) ? weights[(p * 64 + c) * 64 + d] : 0.0f;
                if (e < 4) op0[e] = f2bf(wv); else op1[e - 4] = f2bf(wv);
            }
            *(ushort4*)(wfrag + tw * 8) = o0;
            *(ushort4*)(wfrag + tw * 8 + 4) = o1;
        }
    }
}

__global__ __launch_bounds__(512, 8) void kpconv_main(
    const float* __restrict__ qpts, const float* __restrict__ spts,
    const int* __restrict__ nbr, const float* __restrict__ kpts,
    const unsigned short* __restrict__ xbf, const unsigned short* __restrict__ wfrag,
    float* __restrict__ out)
{
    __shared__ __attribute__((aligned(128))) unsigned char lds[LDS_TOT];
    const int tid = threadIdx.x;
    const int w = tid >> 6;       // 0..7
    const int l = tid & 63;
    const int h = l >> 4;         // 0..3
    const int m = l & 15;

    const int pm = (m < 15) ? m : 14;
    const float kx = kpts[pm * 3 + 0], ky = kpts[pm * 3 + 1], kz = kpts[pm * 3 + 2];

    unsigned char* xw = lds + w * XSLICE;
    unsigned char* posb = lds + LDS_POS + w * POSSTRIDE;   // xy[64] then z[64]

    // ---- tile-invariant bases
    const int eb = (l >> 2) & 1;
    unsigned char* wb2base = xw + (l & 7) * 512 + (l >> 3) * 2;
    unsigned char* wb2E = wb2base + eb * 64;
    unsigned char* wb2O = wb2base + (eb ^ 1) * 64;
    const int xb2 = (l & 3) << 4;
    unsigned char* rb3a = xw + m * 64;
    unsigned char* rb3b = xw + (m ^ 1) * 64;
    const int rxb = (h ^ (m >> 3)) << 4;
    const int voff = l >> 3;
    const int dt = w & 3, kh = w >> 2;
    const unsigned char* abase = lds + m * QSTRIDE + 16 * h;
    const unsigned short* bbase = wfrag + (size_t)((dt * 2 + kh) * 16) * 512 + l * 8;
    const int k0 = kh * 16;
    const int d = dt * 16 + m;

    // ================= PROLOGUE: prefetch + gather tile 0 ==================
    int tile = blockIdx.x;
    int sx[2][4];
    float2 ppxy; float ppz;
    float qxA[2], qyA[2], qzA[2];
    {
        const int* nbase = nbr + (tile * 16 + 2 * w) * 32;
        const int sB = nbase[l];
        #pragma unroll
        for (int i = 0; i < 2; ++i)
            #pragma unroll
            for (int g = 0; g < 4; ++g)
                sx[i][g] = nbase[32 * i + 8 * g + voff];
        ppxy = *(const float2*)(spts + (size_t)sB * 3);
        ppz  = spts[(size_t)sB * 3 + 2];
        #pragma unroll
        for (int i = 0; i < 2; ++i) {
            const int q = tile * 16 + 2 * w + i;
            qxA[i] = qpts[q * 3 + 0]; qyA[i] = qpts[q * 3 + 1]; qzA[i] = qpts[q * 3 + 2];
        }
    }
    int4 xv[2][4];
    #pragma unroll
    for (int i = 0; i < 2; ++i)
        #pragma unroll
        for (int g = 0; g < 4; ++g)
            xv[i][g] = *(const int4*)(xbf + (size_t)sx[i][g] * 64 + (l & 7) * 8);
    // =======================================================================

    for (;;) {
        const int qbase = tile * 16;

        // ---- stage SoA pos (per-wave private; DS-FIFO write->read, no fence)
        *(float2*)(posb + l * 8) = ppxy;
        *(float*)(posb + 512 + l * 4) = ppz;

        uint2 pk0[4];             // deferred wtd pack for query 0 (aliases x buf)

        #pragma unroll
        for (int i = 0; i < 2; ++i) {
            const int ql = 2 * w + i;

            // ---- neighbor_num: ballot per instr-group, bit-fold
            int nn = 0;
            #pragma unroll
            for (int g = 0; g < 4; ++g) {
                const int4 v = xv[i][g];
                unsigned long long b = __ballot((v.x | v.y | v.z | v.w) != 0);
                b |= b >> 4; b |= b >> 2; b |= b >> 1;
                nn += __popcll(b & 0x0101010101010101ULL);
            }
            if (nn < 1) nn = 1;
            if (l == 0) *(int*)(lds + LDS_NN + ql * 4) = nn;

            // ---- scatter-stage x^T (32-bank spread); q1 overwrites after q0
            #pragma unroll
            for (int g = 0; g < 4; ++g) {
                const unsigned short* u8 = (const unsigned short*)&xv[i][g];
                const int gofs = (g << 4) ^ xb2;
                unsigned char* wgE = wb2E + gofs;
                unsigned char* wgO = wb2O + gofs;
                #pragma unroll
                for (int t = 0; t < 4; ++t) {
                    *(unsigned short*)(wgE + t * 128) = u8[2 * t];
                    *(unsigned short*)(wgO + t * 128) = u8[2 * t + 1];
                }
            }

            // ---- A-frag: lane holds w[k=8h+j][p=m]; direct-difference form
            const float bx = qxA[i] + kx, by = qyA[i] + ky, bz = qzA[i] + kz;
            float wv[8];
            #pragma unroll
            for (int j = 0; j < 8; ++j) {
                const float2 sxy = *(const float2*)(posb + (32 * i + j) * 8 + h * 64);
                const float sz = *(const float*)(posb + 512 + (32 * i + j) * 4 + h * 32);
                const float dx = sxy.x - bx, dy = sxy.y - by, dz = sz - bz;
                const float d2 = __builtin_fmaf(dx, dx,
                                 __builtin_fmaf(dy, dy, dz * dz));
                const float s = __builtin_amdgcn_sqrtf(d2);
                wv[j] = fmaxf(__builtin_fmaf(s, -0.5f, 1.0f), 0.0f);
            }
            union { unsigned int dd[4]; short8 s8; } au;
            const bool pad = (m == 15);      // p=15 is the zero pad
            #pragma unroll
            for (int jp = 0; jp < 4; ++jp) {
                const unsigned int pk = (unsigned int)f2bf_fast(wv[2 * jp]) |
                                        ((unsigned int)f2bf_fast(wv[2 * jp + 1]) << 16);
                au.dd[jp] = pad ? 0u : pk;
            }

            // ---- B-frags + step-3 MFMAs
            f32x4 c3[4];
            #pragma unroll
            for (int ct = 0; ct < 4; ++ct) {
                const unsigned char* rb = (ct < 2) ? rb3a : rb3b;
                short8 b3 = *(const short8*)(rb + ct * 1024 + (rxb ^ ((ct & 1) << 5)));
                f32x4 z = {0.f, 0.f, 0.f, 0.f};
                c3[ct] = __builtin_amdgcn_mfma_f32_16x16x32_bf16(au.s8, b3, z, 0, 0, 0);
            }

            // ---- pack wtd (pc' = c*16+p; lane holds p=4h+r, c=16ct+m)
            #pragma unroll
            for (int ct = 0; ct < 4; ++ct) {
                uint2 pkv;
                pkv.x = (unsigned int)f2bf_fast(c3[ct][0]) | ((unsigned int)f2bf_fast(c3[ct][1]) << 16);
                pkv.y = (unsigned int)f2bf_fast(c3[ct][2]) | ((unsigned int)f2bf_fast(c3[ct][3]) << 16);
                if (i == 0) {
                    pk0[ct] = pkv;           // row 2w aliases x buf: defer
                } else {
                    *(uint2*)(lds + ql * QSTRIDE + (ct * 16 + m) * 32 + h * 8) = pkv;
                }
            }
        }

        // ---- flush query 0's deferred wtd row
        #pragma unroll
        for (int ct = 0; ct < 4; ++ct)
            *(uint2*)(lds + (2 * w) * QSTRIDE + (ct * 16 + m) * 32 + h * 8) = pk0[ct];

        // ---- PREFETCH(t+1): nbr/sidx/spts/qpts into regs, in flight over
        //      bar1 + phase 4 (their consumers are next iteration's loop top)
        const int next = tile + PGRID;
        const bool more = next < NTILES;
        if (more) {
            const int* nbase = nbr + (next * 16 + 2 * w) * 32;
            const int sB = nbase[l];
            #pragma unroll
            for (int i = 0; i < 2; ++i)
                #pragma unroll
                for (int g = 0; g < 4; ++g)
                    sx[i][g] = nbase[32 * i + 8 * g + voff];
            ppxy = *(const float2*)(spts + (size_t)sB * 3);
            ppz  = spts[(size_t)sB * 3 + 2];
            #pragma unroll
            for (int i = 0; i < 2; ++i) {
                const int q = next * 16 + 2 * w + i;
                qxA[i] = qpts[q * 3 + 0]; qyA[i] = qpts[q * 3 + 1]; qzA[i] = qpts[q * 3 + 2];
            }
        }

        __syncthreads();          // bar1: wtd ready for phase 4

        // ---- phase 4 (split-K): wave w -> d-tile (w&3), k-half (w>>2)
        f32x4 acc0 = {0.f, 0.f, 0.f, 0.f}, acc1 = {0.f, 0.f, 0.f, 0.f};
        #pragma unroll
        for (int j = 0; j < 8; ++j) {
            short8 a4a = *(const short8*)(abase + (k0 + j) * 64);
            short8 b4a = *(const short8*)(bbase + j * 512);
            acc0 = __builtin_amdgcn_mfma_f32_16x16x32_bf16(a4a, b4a, acc0, 0, 0, 0);
            short8 a4b = *(const short8*)(abase + (k0 + 8 + j) * 64);
            short8 b4b = *(const short8*)(bbase + (8 + j) * 512);
            acc1 = __builtin_amdgcn_mfma_f32_16x16x32_bf16(a4b, b4b, acc1, 0, 0, 0);
        }

        // ---- issue xv(t+1): VMEM only, overlaps red exchange + epilogue
        if (more) {
            #pragma unroll
            for (int i = 0; i < 2; ++i)
                #pragma unroll
                for (int g = 0; g < 4; ++g)
                    xv[i][g] = *(const int4*)(xbf + (size_t)sx[i][g] * 64 + (l & 7) * 8);
        }

        if (kh == 1) {
            f32x4 acc = acc0 + acc1;
            *(f32x4*)(lds + LDS_RED + dt * 1024 + l * 16) = acc;
        }
        __syncthreads();          // bar2: red ready
        if (kh == 0) {
            f32x4 part = *(const f32x4*)(lds + LDS_RED + dt * 1024 + l * 16);
            #pragma unroll
            for (int r = 0; r < 4; ++r) {
                const int qr = 4 * h + r;
                const int nn = *(const int*)(lds + LDS_NN + qr * 4);
                out[(size_t)(qbase + qr) * 64 + d] =
                    (acc0[r] + acc1[r] + part[r]) * (1.0f / (float)nn);
            }
        }

        if (!more) break;
        tile = next;
        __syncthreads();          // bar3: red/nn consumed -> pos/x/wtd reusable
    }
}

extern "C" void kernel_launch(void* const* d_in, const int* in_sizes, int n_in,
                              void* d_out, int out_size, void* d_ws, size_t ws_size,
                              hipStream_t stream) {
    const float* s_feats = (const float*)d_in[0];
    const float* q_points = (const float*)d_in[1];
    const float* s_points = (const float*)d_in[2];
    const int* nbr = (const int*)d_in[3];
    const float* kpts = (const float*)d_in[4];
    const float* wts = (const float*)d_in[5];
    float* out = (float*)d_out;

    unsigned short* xbf = (unsigned short*)d_ws;
    unsigned short* wfrag = (unsigned short*)((char*)d_ws + WT_BYTE_OFF);

    // prekernel: 800000 threads for xbf + 8192 for wfrag -> 3157 blocks
    hipLaunchKernelGGL(kpconv_pre, dim3(3157), dim3(256), 0, stream,
                       s_feats, wts, xbf, wfrag);
    // persistent main: 1024 blocks grid-stride over 3125 tiles
    hipLaunchKernelGGL(kpconv_main, dim3(PGRID), dim3(512), 0, stream,
                       q_points, s_points, nbr, kpts, xbf, wfrag, out);
}

// Round 10
// 285.635 us; speedup vs baseline: 1.3002x; 1.3002x over previous
//
#include <hip/hip_runtime.h>
#include <hip/hip_bf16.h>

typedef __attribute__((ext_vector_type(8))) short short8;
typedef __attribute__((ext_vector_type(4))) float f32x4;

// ws layout: xbf (bf16 s_feats) at 0, 6,400,000 B; wfrag (fragment-major W) at
// 6,400,000, 131,072 B. wfrag: fragment f = (dt*2+kh)*16+jj holds, at lane l,
// elems W[pc = (kh*16+jj)*32 + 8*(l>>4) + e][d = dt*16 + (l&15)] at f*512+l*8+e.
#define WT_BYTE_OFF 6400000

// LDS layout (bytes) -- round-5 structure, unchanged:
//   wtd:  [0, 33024) = 16 queries x QSTRIDE(2064); wave w owns rows 2w,2w+1
//   x:    wave w's x^T tile [c-slot=64][k-swizzled], 4096 B, aliases slice head.
//         slot(c) = c ^ ((c>>5)&1) (32-bank write spread, 2 lanes/bank free)
//   nn:   [33024, 33088) 16 ints
//   pos:  [33088, +8*768) per-wave SoA xy float2[64] + z float[64]; DS-FIFO
//   red:  [33088, 37184) phase-4 partials -- aliases pos ACROSS barriers;
//         bar3 protects pos(t+1) from racing red(t) (verified r8 correctness).
#define QSTRIDE   2064
#define XSLICE    4128
#define LDS_NN    33024
#define LDS_POS   33088
#define POSSTRIDE 768
#define LDS_RED   33088
#define LDS_TOT   (33088 + 8*768)

#define NTILES    3125
#define PGRID     1024   // 4 blocks/CU x 256 CU: fully resident, grid-stride

__device__ inline unsigned short f2bf(float x) {           // RNE, pre-kernel
    unsigned int u = __float_as_uint(x);
    unsigned int r = (u + 0x7FFFu + ((u >> 16) & 1u)) >> 16;
    return (unsigned short)r;
}

__device__ inline unsigned short f2bf_fast(float x) {      // native RNE convert
    __hip_bfloat16 b = __float2bfloat16(x);
    return *reinterpret_cast<unsigned short*>(&b);
}

__global__ void kpconv_pre(const float* __restrict__ s_feats,
                           const float* __restrict__ weights,
                           unsigned short* __restrict__ xbf,
                           unsigned short* __restrict__ wfrag) {
    int t = blockIdx.x * 256 + threadIdx.x;
    if (t < 800000) {                       // 3.2M elems / 4
        int i = t * 4;
        float4 v = *(const float4*)(s_feats + i);
        ushort4 o;
        o.x = f2bf(v.x); o.y = f2bf(v.y); o.z = f2bf(v.z); o.w = f2bf(v.w);
        *(ushort4*)(xbf + i) = o;
    } else {
        int tw = t - 800000;
        if (tw < 8192) {                    // 128 frags x 64 lanes, 16 B each
            const int f = tw >> 6, l = tw & 63;
            const int m = l & 15, h = l >> 4;
            const int dt = f >> 5, kh = (f >> 4) & 1, jj = f & 15;
            const int d = dt * 16 + m;
            const int pcb = (kh * 16 + jj) * 32 + 8 * h;
            ushort4 o0, o1;
            unsigned short* op0 = (unsigned short*)&o0;
            unsigned short* op1 = (unsigned short*)&o1;
            #pragma unroll
            for (int e = 0; e < 8; ++e) {
                const int pc = pcb + e;
                const int p = pc & 15, c = pc >> 4;
                const float wv = (p < 15) ? weights[(p * 64 + c) * 64 + d] : 0.0f;
                if (e < 4) op0[e] = f2bf(wv); else op1[e - 4] = f2bf(wv);
            }
            *(ushort4*)(wfrag + tw * 8) = o0;
            *(ushort4*)(wfrag + tw * 8 + 4) = o1;
        }
    }
}

__global__ __launch_bounds__(512, 8) void kpconv_main(
    const float* __restrict__ qpts, const float* __restrict__ spts,
    const int* __restrict__ nbr, const float* __restrict__ kpts,
    const unsigned short* __restrict__ xbf, const unsigned short* __restrict__ wfrag,
    float* __restrict__ out)
{
    __shared__ __attribute__((aligned(128))) unsigned char lds[LDS_TOT];
    const int tid = threadIdx.x;
    const int w = tid >> 6;       // 0..7
    const int l = tid & 63;
    const int h = l >> 4;         // 0..3
    const int m = l & 15;

    const int pm = (m < 15) ? m : 14;
    const float kx = kpts[pm * 3 + 0], ky = kpts[pm * 3 + 1], kz = kpts[pm * 3 + 2];

    unsigned char* xw = lds + w * XSLICE;
    unsigned char* posb = lds + LDS_POS + w * POSSTRIDE;   // xy[64] then z[64]

    // ---- tile-invariant bases
    const int eb = (l >> 2) & 1;
    unsigned char* wb2base = xw + (l & 7) * 512 + (l >> 3) * 2;
    unsigned char* wb2E = wb2base + eb * 64;
    unsigned char* wb2O = wb2base + (eb ^ 1) * 64;
    const int xb2 = (l & 3) << 4;
    unsigned char* rb3a = xw + m * 64;
    unsigned char* rb3b = xw + (m ^ 1) * 64;
    const int rxb = (h ^ (m >> 3)) << 4;
    const int voff = l >> 3;
    const int dt = w & 3, kh = w >> 2;
    const unsigned char* abase = lds + m * QSTRIDE + 16 * h;
    const unsigned short* bbase = wfrag + (size_t)((dt * 2 + kh) * 16) * 512 + l * 8;
    const int k0 = kh * 16;
    const int d = dt * 16 + m;

    // ===== PROLOGUE: index/pos/query chain for tile 0 (17 live regs) =======
    int tile = blockIdx.x;
    int sx[2][4];
    float2 ppxy; float ppz;
    float qxA[2], qyA[2], qzA[2];
    {
        const int* nbase = nbr + (tile * 16 + 2 * w) * 32;
        const int sB = nbase[l];
        #pragma unroll
        for (int i = 0; i < 2; ++i)
            #pragma unroll
            for (int g = 0; g < 4; ++g)
                sx[i][g] = nbase[32 * i + 8 * g + voff];
        ppxy = *(const float2*)(spts + (size_t)sB * 3);
        ppz  = spts[(size_t)sB * 3 + 2];
        #pragma unroll
        for (int i = 0; i < 2; ++i) {
            const int q = tile * 16 + 2 * w + i;
            qxA[i] = qpts[q * 3 + 0]; qyA[i] = qpts[q * 3 + 1]; qzA[i] = qpts[q * 3 + 2];
        }
    }
    // =======================================================================

    for (;;) {
        const int qbase = tile * 16;

        // ---- xv gathers at loop top (round-5 live range: no cross-barrier
        //      pressure). sx is already resolved -> gathers issue immediately.
        int4 xv[2][4];
        #pragma unroll
        for (int i = 0; i < 2; ++i)
            #pragma unroll
            for (int g = 0; g < 4; ++g)
                xv[i][g] = *(const int4*)(xbf + (size_t)sx[i][g] * 64 + (l & 7) * 8);

        // ---- stage SoA pos (per-wave private; DS-FIFO write->read, no fence)
        *(float2*)(posb + l * 8) = ppxy;
        *(float*)(posb + 512 + l * 4) = ppz;

        uint2 pk0[4];             // deferred wtd pack for query 0 (aliases x buf)

        #pragma unroll
        for (int i = 0; i < 2; ++i) {
            const int ql = 2 * w + i;

            // ---- neighbor_num: ballot per instr-group, bit-fold
            int nn = 0;
            #pragma unroll
            for (int g = 0; g < 4; ++g) {
                const int4 v = xv[i][g];
                unsigned long long b = __ballot((v.x | v.y | v.z | v.w) != 0);
                b |= b >> 4; b |= b >> 2; b |= b >> 1;
                nn += __popcll(b & 0x0101010101010101ULL);
            }
            if (nn < 1) nn = 1;
            if (l == 0) *(int*)(lds + LDS_NN + ql * 4) = nn;

            // ---- scatter-stage x^T (32-bank spread); q1 overwrites after q0
            #pragma unroll
            for (int g = 0; g < 4; ++g) {
                const unsigned short* u8 = (const unsigned short*)&xv[i][g];
                const int gofs = (g << 4) ^ xb2;
                unsigned char* wgE = wb2E + gofs;
                unsigned char* wgO = wb2O + gofs;
                #pragma unroll
                for (int t = 0; t < 4; ++t) {
                    *(unsigned short*)(wgE + t * 128) = u8[2 * t];
                    *(unsigned short*)(wgO + t * 128) = u8[2 * t + 1];
                }
            }

            // ---- A-frag: lane holds w[k=8h+j][p=m]; direct-difference form
            const float bx = qxA[i] + kx, by = qyA[i] + ky, bz = qzA[i] + kz;
            float wv[8];
            #pragma unroll
            for (int j = 0; j < 8; ++j) {
                const float2 sxy = *(const float2*)(posb + (32 * i + j) * 8 + h * 64);
                const float sz = *(const float*)(posb + 512 + (32 * i + j) * 4 + h * 32);
                const float dx = sxy.x - bx, dy = sxy.y - by, dz = sz - bz;
                const float d2 = __builtin_fmaf(dx, dx,
                                 __builtin_fmaf(dy, dy, dz * dz));
                const float s = __builtin_amdgcn_sqrtf(d2);
                wv[j] = fmaxf(__builtin_fmaf(s, -0.5f, 1.0f), 0.0f);
            }
            union { unsigned int dd[4]; short8 s8; } au;
            const bool pad = (m == 15);      // p=15 is the zero pad
            #pragma unroll
            for (int jp = 0; jp < 4; ++jp) {
                const unsigned int pk = (unsigned int)f2bf_fast(wv[2 * jp]) |
                                        ((unsigned int)f2bf_fast(wv[2 * jp + 1]) << 16);
                au.dd[jp] = pad ? 0u : pk;
            }

            // ---- B-frags + step-3 MFMAs
            f32x4 c3[4];
            #pragma unroll
            for (int ct = 0; ct < 4; ++ct) {
                const unsigned char* rb = (ct < 2) ? rb3a : rb3b;
                short8 b3 = *(const short8*)(rb + ct * 1024 + (rxb ^ ((ct & 1) << 5)));
                f32x4 z = {0.f, 0.f, 0.f, 0.f};
                c3[ct] = __builtin_amdgcn_mfma_f32_16x16x32_bf16(au.s8, b3, z, 0, 0, 0);
            }

            // ---- pack wtd (pc' = c*16+p; lane holds p=4h+r, c=16ct+m)
            #pragma unroll
            for (int ct = 0; ct < 4; ++ct) {
                uint2 pkv;
                pkv.x = (unsigned int)f2bf_fast(c3[ct][0]) | ((unsigned int)f2bf_fast(c3[ct][1]) << 16);
                pkv.y = (unsigned int)f2bf_fast(c3[ct][2]) | ((unsigned int)f2bf_fast(c3[ct][3]) << 16);
                if (i == 0) {
                    pk0[ct] = pkv;           // row 2w aliases x buf: defer
                } else {
                    *(uint2*)(lds + ql * QSTRIDE + (ct * 16 + m) * 32 + h * 8) = pkv;
                }
            }
        }

        // ---- flush query 0's deferred wtd row
        #pragma unroll
        for (int ct = 0; ct < 4; ++ct)
            *(uint2*)(lds + (2 * w) * QSTRIDE + (ct * 16 + m) * 32 + h * 8) = pk0[ct];

        // ---- PREFETCH(t+1): index/pos/query chain only (~17 regs, no spill);
        //      latency hides under bar1 + phase 4 + red exchange.
        const int next = tile + PGRID;
        const bool more = next < NTILES;
        if (more) {
            const int* nbase = nbr + (next * 16 + 2 * w) * 32;
            const int sB = nbase[l];
            #pragma unroll
            for (int i = 0; i < 2; ++i)
                #pragma unroll
                for (int g = 0; g < 4; ++g)
                    sx[i][g] = nbase[32 * i + 8 * g + voff];
            ppxy = *(const float2*)(spts + (size_t)sB * 3);
            ppz  = spts[(size_t)sB * 3 + 2];
            #pragma unroll
            for (int i = 0; i < 2; ++i) {
                const int q = next * 16 + 2 * w + i;
                qxA[i] = qpts[q * 3 + 0]; qyA[i] = qpts[q * 3 + 1]; qzA[i] = qpts[q * 3 + 2];
            }
        }

        __syncthreads();          // bar1: wtd ready for phase 4

        // ---- phase 4 (split-K): wave w -> d-tile (w&3), k-half (w>>2)
        f32x4 acc0 = {0.f, 0.f, 0.f, 0.f}, acc1 = {0.f, 0.f, 0.f, 0.f};
        #pragma unroll
        for (int j = 0; j < 8; ++j) {
            short8 a4a = *(const short8*)(abase + (k0 + j) * 64);
            short8 b4a = *(const short8*)(bbase + j * 512);
            acc0 = __builtin_amdgcn_mfma_f32_16x16x32_bf16(a4a, b4a, acc0, 0, 0, 0);
            short8 a4b = *(const short8*)(abase + (k0 + 8 + j) * 64);
            short8 b4b = *(const short8*)(bbase + (8 + j) * 512);
            acc1 = __builtin_amdgcn_mfma_f32_16x16x32_bf16(a4b, b4b, acc1, 0, 0, 0);
        }

        if (kh == 1) {
            f32x4 acc = acc0 + acc1;
            *(f32x4*)(lds + LDS_RED + dt * 1024 + l * 16) = acc;
        }
        __syncthreads();          // bar2: red ready
        if (kh == 0) {
            f32x4 part = *(const f32x4*)(lds + LDS_RED + dt * 1024 + l * 16);
            #pragma unroll
            for (int r = 0; r < 4; ++r) {
                const int qr = 4 * h + r;
                const int nn = *(const int*)(lds + LDS_NN + qr * 4);
                out[(size_t)(qbase + qr) * 64 + d] =
                    (acc0[r] + acc1[r] + part[r]) * (1.0f / (float)nn);
            }
        }

        if (!more) break;
        tile = next;
        __syncthreads();          // bar3: red/nn consumed -> pos/x/wtd reusable
    }
}

extern "C" void kernel_launch(void* const* d_in, const int* in_sizes, int n_in,
                              void* d_out, int out_size, void* d_ws, size_t ws_size,
                              hipStream_t stream) {
    const float* s_feats = (const float*)d_in[0];
    const float* q_points = (const float*)d_in[1];
    const float* s_points = (const float*)d_in[2];
    const int* nbr = (const int*)d_in[3];
    const float* kpts = (const float*)d_in[4];
    const float* wts = (const float*)d_in[5];
    float* out = (float*)d_out;

    unsigned short* xbf = (unsigned short*)d_ws;
    unsigned short* wfrag = (unsigned short*)((char*)d_ws + WT_BYTE_OFF);

    // prekernel: 800000 threads for xbf + 8192 for wfrag -> 3157 blocks
    hipLaunchKernelGGL(kpconv_pre, dim3(3157), dim3(256), 0, stream,
                       s_feats, wts, xbf, wfrag);
    // persistent main: 1024 blocks grid-stride over 3125 tiles
    hipLaunchKernelGGL(kpconv_main, dim3(PGRID), dim3(512), 0, stream,
                       q_points, s_points, nbr, kpts, xbf, wfrag, out);
}

// Round 11
// 53.764 us; speedup vs baseline: 6.9074x; 5.3127x over previous
//
#include <hip/hip_runtime.h>
#include <hip/hip_bf16.h>

typedef __attribute__((ext_vector_type(8))) short short8;
typedef __attribute__((ext_vector_type(4))) float f32x4;

// ws layout: xbf (bf16 s_feats) at 0, 6,400,000 B; wfrag (fragment-major W) at
// 6,400,000, 131,072 B. wfrag: fragment f = (dt*2+kh)*16+jj holds, at lane l,
// elems W[pc = (kh*16+jj)*32 + 8*(l>>4) + e][d = dt*16 + (l&15)] at f*512+l*8+e.
#define WT_BYTE_OFF 6400000

// LDS layout (bytes):
//   wtd:  [0, 33024) = 16 queries x QSTRIDE(2064) (elems pc' = c*16+p, bf16)
//         wave w owns rows 2w,2w+1 = [w*4128, (w+1)*4128)
//   x:    wave w's x^T tile [c-slot=64][k-swizzled], 4096 B, aliases slice head.
//         addr(c,k) = slot(c)*64 + ((k>>3) ^ ((c>>3)&3))*16 + (k&7)*2
//         with slot(c) = c ^ ((c>>5)&1)  (32-bank write spread, 2 lanes/bank)
//   nn:   [33024, 33088) 16 ints
//   pos:  [33088, +8*768) per-wave SoA: xy float2[64] (512 B) + z float[64]
//         (256 B). 768 B/wave -> LDS_TOT 39232 < 40960 => 4 blocks/CU.
//         pos write->read ordering is per-wave DS-FIFO (no fence needed).
//   red:  [33088, 37184) phase-4 partials -- aliases pos across the barrier
// NOTE: persistent-loop variants (r8/r9) spill: the 4-blocks/CU occupancy
// requires 8 waves/SIMD => 64-VGPR cap, which a cross-backedge prefetch
// chain cannot fit. Straight-line structure is the only spill-free form.
#define QSTRIDE   2064
#define XSLICE    4128
#define LDS_NN    33024
#define LDS_POS   33088
#define POSSTRIDE 768
#define LDS_RED   33088
#define LDS_TOT   (33088 + 8*768)

__device__ inline unsigned short f2bf(float x) {           // RNE, pre-kernel
    unsigned int u = __float_as_uint(x);
    unsigned int r = (u + 0x7FFFu + ((u >> 16) & 1u)) >> 16;
    return (unsigned short)r;
}

__device__ inline unsigned short f2bf_fast(float x) {      // native RNE convert
    __hip_bfloat16 b = __float2bfloat16(x);
    return *reinterpret_cast<unsigned short*>(&b);
}

__global__ void kpconv_pre(const float* __restrict__ s_feats,
                           const float* __restrict__ weights,
                           unsigned short* __restrict__ xbf,
                           unsigned short* __restrict__ wfrag) {
    int t = blockIdx.x * 256 + threadIdx.x;
    if (t < 800000) {                       // 3.2M elems / 4
        int i = t * 4;
        float4 v = *(const float4*)(s_feats + i);
        ushort4 o;
        o.x = f2bf(v.x); o.y = f2bf(v.y); o.z = f2bf(v.z); o.w = f2bf(v.w);
        *(ushort4*)(xbf + i) = o;
    } else {
        int tw = t - 800000;
        if (tw < 8192) {                    // 128 frags x 64 lanes, 16 B each
            const int f = tw >> 6, l = tw & 63;
            const int m = l & 15, h = l >> 4;
            const int dt = f >> 5, kh = (f >> 4) & 1, jj = f & 15;
            const int d = dt * 16 + m;
            const int pcb = (kh * 16 + jj) * 32 + 8 * h;
            ushort4 o0, o1;
            unsigned short* op0 = (unsigned short*)&o0;
            unsigned short* op1 = (unsigned short*)&o1;
            #pragma unroll
            for (int e = 0; e < 8; ++e) {
                const int pc = pcb + e;
                const int p = pc & 15, c = pc >> 4;
                const float wv = (p < 15) ? weights[(p * 64 + c) * 64 + d] : 0.0f;
                if (e < 4) op0[e] = f2bf(wv); else op1[e - 4] = f2bf(wv);
            }
            *(ushort4*)(wfrag + tw * 8) = o0;
            *(ushort4*)(wfrag + tw * 8 + 4) = o1;
        }
    }
}

__global__ __launch_bounds__(512, 8) void kpconv_main(
    const float* __restrict__ qpts, const float* __restrict__ spts,
    const int* __restrict__ nbr, const float* __restrict__ kpts,
    const unsigned short* __restrict__ xbf, const unsigned short* __restrict__ wfrag,
    float* __restrict__ out)
{
    __shared__ __attribute__((aligned(128))) unsigned char lds[LDS_TOT];
    const int tid = threadIdx.x;
    const int w = tid >> 6;       // 0..7
    const int l = tid & 63;
    const int h = l >> 4;         // 0..3
    const int m = l & 15;
    const int qbase = blockIdx.x * 16;

    const int pm = (m < 15) ? m : 14;
    const float kx = kpts[pm * 3 + 0], ky = kpts[pm * 3 + 1], kz = kpts[pm * 3 + 2];

    unsigned char* xw = lds + w * XSLICE;
    unsigned char* posb = lds + LDS_POS + w * POSSTRIDE;   // xy[64] then z[64]

    // ============ LOAD-ISSUE REGION: all gathers in flight together ========
    // ---- ONE coalesced load: lane l = (query l>>5, neighbor l&31)
    const int* nbase = nbr + (qbase + 2 * w) * 32;
    const int sBoth = nbase[l];

    // ---- staging row indices: direct imm-offset loads (nbr row is L1-hot)
    const int voff = l >> 3;
    int sidx[2][4];
    #pragma unroll
    for (int i = 0; i < 2; ++i)
        #pragma unroll
        for (int g = 0; g < 4; ++g)
            sidx[i][g] = nbase[32 * i + 8 * g + voff];

    // ---- position gather (depends only on sBoth)
    const float2 pxy = *(const float2*)(spts + (size_t)sBoth * 3);
    const float pz = spts[(size_t)sBoth * 3 + 2];

    // ---- xbf gathers, both queries upfront: instr (i,g) reads 8 FULL rows.
    //      Issued while the spts gather is still in flight (no fence between).
    int4 xv[2][4];
    #pragma unroll
    for (int i = 0; i < 2; ++i)
        #pragma unroll
        for (int g = 0; g < 4; ++g)
            xv[i][g] = *(const int4*)(xbf + (size_t)sidx[i][g] * 64 + (l & 7) * 8);
    // =======================================================================

    // ---- stage SoA {xy}[l], {z}[l]: counted vmcnt waits only for spts loads;
    //      the 8 xv gathers remain outstanding.
    *(float2*)(posb + l * 8) = pxy;
    *(float*)(posb + 512 + l * 4) = pz;

    // ---- x-tile write bases: column slot = c ^ ((c>>5)&1); c = 8*(l&7)+e
    const int eb = (l >> 2) & 1;
    unsigned char* wb2base = xw + (l & 7) * 512 + (l >> 3) * 2;
    unsigned char* wb2E = wb2base + eb * 64;
    unsigned char* wb2O = wb2base + (eb ^ 1) * 64;
    const int xb2 = (l & 3) << 4;
    // read bases: ct<2 -> slot m; ct>=2 -> slot m^1 (bit0 column flip)
    unsigned char* rb3a = xw + m * 64;
    unsigned char* rb3b = xw + (m ^ 1) * 64;
    const int rxb = (h ^ (m >> 3)) << 4;

    uint2 pk0[4];                 // deferred wtd pack for query 0 (aliases x buf)

    #pragma unroll
    for (int i = 0; i < 2; ++i) {
        const int ql = 2 * w + i;
        const int q = qbase + ql;

        // ---- neighbor_num: ballot per instr-group, bit-fold (row = 8-lane octet)
        int nn = 0;
        #pragma unroll
        for (int g = 0; g < 4; ++g) {
            const int4 v = xv[i][g];
            unsigned long long b = __ballot((v.x | v.y | v.z | v.w) != 0);
            b |= b >> 4; b |= b >> 2; b |= b >> 1;
            nn += __popcll(b & 0x0101010101010101ULL);
        }
        if (nn < 1) nn = 1;
        if (l == 0) *(int*)(lds + LDS_NN + ql * 4) = nn;

        // ---- scatter-stage x^T (32-bank spread); q1 overwrites after q0 use
        #pragma unroll
        for (int g = 0; g < 4; ++g) {
            const unsigned short* u8 = (const unsigned short*)&xv[i][g];
            const int gofs = (g << 4) ^ xb2;
            unsigned char* wgE = wb2E + gofs;
            unsigned char* wgO = wb2O + gofs;
            #pragma unroll
            for (int t = 0; t < 4; ++t) {
                *(unsigned short*)(wgE + t * 128) = u8[2 * t];
                *(unsigned short*)(wgO + t * 128) = u8[2 * t + 1];
            }
        }

        // ---- A-frag: lane holds w[k=8h+j][p=m]; direct-difference form
        const float qx = qpts[q * 3 + 0], qy = qpts[q * 3 + 1], qz = qpts[q * 3 + 2];
        const float bx = qx + kx, by = qy + ky, bz = qz + kz;
        float wv[8];
        #pragma unroll
        for (int j = 0; j < 8; ++j) {
            const float2 sxy = *(const float2*)(posb + (32 * i + j) * 8 + h * 64);
            const float sz = *(const float*)(posb + 512 + (32 * i + j) * 4 + h * 32);
            const float dx = sxy.x - bx, dy = sxy.y - by, dz = sz - bz;
            const float d2 = __builtin_fmaf(dx, dx,
                             __builtin_fmaf(dy, dy, dz * dz));
            const float s = __builtin_amdgcn_sqrtf(d2);
            wv[j] = fmaxf(__builtin_fmaf(s, -0.5f, 1.0f), 0.0f);
        }
        union { unsigned int d[4]; short8 s8; } au;
        const bool pad = (m == 15);          // p=15 is the zero pad
        #pragma unroll
        for (int jp = 0; jp < 4; ++jp) {
            const unsigned int pk = (unsigned int)f2bf_fast(wv[2 * jp]) |
                                    ((unsigned int)f2bf_fast(wv[2 * jp + 1]) << 16);
            au.d[jp] = pad ? 0u : pk;
        }

        // ---- B-frags + step-3 MFMAs (b128 reads, 8 lanes/quad balanced)
        //      T5: boost wave priority through the MFMA cluster (4 independent
        //      blocks/CU are phase-skewed -> scheduler has something to arbitrate)
        f32x4 c3[4];
        __builtin_amdgcn_s_setprio(1);
        #pragma unroll
        for (int ct = 0; ct < 4; ++ct) {
            const unsigned char* rb = (ct < 2) ? rb3a : rb3b;
            short8 b3 = *(const short8*)(rb + ct * 1024 + (rxb ^ ((ct & 1) << 5)));
            f32x4 z = {0.f, 0.f, 0.f, 0.f};
            c3[ct] = __builtin_amdgcn_mfma_f32_16x16x32_bf16(au.s8, b3, z, 0, 0, 0);
        }
        __builtin_amdgcn_s_setprio(0);

        // ---- pack wtd (pc' = c*16+p; lane holds p=4h+r, c=16ct+m)
        #pragma unroll
        for (int ct = 0; ct < 4; ++ct) {
            uint2 pkv;
            pkv.x = (unsigned int)f2bf_fast(c3[ct][0]) | ((unsigned int)f2bf_fast(c3[ct][1]) << 16);
            pkv.y = (unsigned int)f2bf_fast(c3[ct][2]) | ((unsigned int)f2bf_fast(c3[ct][3]) << 16);
            if (i == 0) {
                pk0[ct] = pkv;               // row 2w aliases x buf: defer
            } else {
                *(uint2*)(lds + ql * QSTRIDE + (ct * 16 + m) * 32 + h * 8) = pkv;
            }
        }
    }

    // ---- flush query 0's deferred wtd row
    #pragma unroll
    for (int ct = 0; ct < 4; ++ct)
        *(uint2*)(lds + (2 * w) * QSTRIDE + (ct * 16 + m) * 32 + h * 8) = pk0[ct];

    __syncthreads();

    // ---- phase 4 (split-K): wave w -> d-tile (w&3), k-half (w>>2)
    const int dt = w & 3, kh = w >> 2;
    const int d = dt * 16 + m;
    f32x4 acc0 = {0.f, 0.f, 0.f, 0.f}, acc1 = {0.f, 0.f, 0.f, 0.f};
    const unsigned char* abase = lds + m * QSTRIDE + 16 * h;
    const unsigned short* bbase = wfrag + (size_t)((dt * 2 + kh) * 16) * 512 + l * 8;
    const int k0 = kh * 16;
    __builtin_amdgcn_s_setprio(1);
    #pragma unroll
    for (int j = 0; j < 8; ++j) {
        short8 a4a = *(const short8*)(abase + (k0 + j) * 64);
        short8 b4a = *(const short8*)(bbase + j * 512);
        acc0 = __builtin_amdgcn_mfma_f32_16x16x32_bf16(a4a, b4a, acc0, 0, 0, 0);
        short8 a4b = *(const short8*)(abase + (k0 + 8 + j) * 64);
        short8 b4b = *(const short8*)(bbase + (8 + j) * 512);
        acc1 = __builtin_amdgcn_mfma_f32_16x16x32_bf16(a4b, b4b, acc1, 0, 0, 0);
    }
    __builtin_amdgcn_s_setprio(0);

    if (kh == 1) {
        f32x4 acc = acc0 + acc1;
        *(f32x4*)(lds + LDS_RED + dt * 1024 + l * 16) = acc;
    }
    __syncthreads();
    if (kh == 0) {
        f32x4 part = *(const f32x4*)(lds + LDS_RED + dt * 1024 + l * 16);
        #pragma unroll
        for (int r = 0; r < 4; ++r) {
            const int qr = 4 * h + r;
            const int nn = *(const int*)(lds + LDS_NN + qr * 4);
            out[(size_t)(qbase + qr) * 64 + d] =
                (acc0[r] + acc1[r] + part[r]) * (1.0f / (float)nn);
        }
    }
}

extern "C" void kernel_launch(void* const* d_in, const int* in_sizes, int n_in,
                              void* d_out, int out_size, void* d_ws, size_t ws_size,
                              hipStream_t stream) {
    const float* s_feats = (const float*)d_in[0];
    const float* q_points = (const float*)d_in[1];
    const float* s_points = (const float*)d_in[2];
    const int* nbr = (const int*)d_in[3];
    const float* kpts = (const float*)d_in[4];
    const float* wts = (const float*)d_in[5];
    float* out = (float*)d_out;

    unsigned short* xbf = (unsigned short*)d_ws;
    unsigned short* wfrag = (unsigned short*)((char*)d_ws + WT_BYTE_OFF);

    // prekernel: 800000 threads for xbf + 8192 for wfrag -> 3157 blocks
    hipLaunchKernelGGL(kpconv_pre, dim3(3157), dim3(256), 0, stream,
                       s_feats, wts, xbf, wfrag);
    hipLaunchKernelGGL(kpconv_main, dim3(3125), dim3(512), 0, stream,
                       q_points, s_points, nbr, kpts, xbf, wfrag, out);
}

// Round 12
// 52.263 us; speedup vs baseline: 7.1058x; 1.0287x over previous
//
#include <hip/hip_runtime.h>
#include <hip/hip_bf16.h>

typedef __attribute__((ext_vector_type(8))) short short8;
typedef __attribute__((ext_vector_type(4))) float f32x4;

// ws layout: xbf (bf16 s_feats) at 0, 6,400,000 B; wfrag (fragment-major W) at
// 6,400,000, 131,072 B. wfrag: fragment f = (dt*2+kh)*16+jj holds, at lane l,
// elems W[pc = (kh*16+jj)*32 + 8*(l>>4) + e][d = dt*16 + (l&15)] at f*512+l*8+e.
#define WT_BYTE_OFF 6400000

// LDS layout (bytes):
//   wtd:  [0, 33024) = 16 queries x QSTRIDE(2064) (elems pc' = c*16+p, bf16)
//         wave w owns rows 2w,2w+1 = [w*4128, (w+1)*4128)
//   x:    wave w's x^T tile [c-slot=64][k-swizzled], 4096 B, aliases slice head.
//         addr(c,k) = slot(c)*64 + ((k>>3) ^ ((c>>3)&3))*16 + (k&7)*2
//         with slot(c) = c ^ ((c>>5)&1)  <- bit0 column flip for c>=32:
//         spreads the b16 scatter-writes across ALL 32 banks (2 lanes/bank,
//         free) instead of 16 banks x 4 lanes. Read side: base m^1 for ct>=2.
//   nn:   [33024, 33088) 16 ints
//   pos:  [33088, +8*768) per-wave SoA: xy float2[64] (512 B) + z float[64]
//         (256 B). 768 B/wave -> LDS_TOT 39232 < 40960 => 4 blocks/CU.
//         pos write->read ordering is per-wave DS-FIFO (no fence needed; a
//         lgkmcnt(0)+sched_barrier here serializes spts-wait before xv issue).
//   red:  [33088, 37184) phase-4 partials -- aliases pos across the barrier
//
// Session ledger (what was measured, rounds 0-10):
//   - write-spread swizzle: conflicts 8.0M->4.8M, time ~0 (LDS not critical)
//   - occupancy 3->4 blocks/CU via pos SoA shrink: -3.8 us  (the big win)
//   - all-gathers-in-flight + fence removal: -1.4 us
//   - TA-txn reduction / tr_b16 / 256t-full-K / persistent-prefetch /
//     setprio: null or negative (persistent spills: 8 w/SIMD => 64-VGPR cap)
// Remaining stall is the per-block gather dependence chain; it cannot be
// pipelined across tiles without breaking the 64-VGPR budget that the
// 4-blocks/CU occupancy requires. Latency-structural floor.
#define QSTRIDE   2064
#define XSLICE    4128
#define LDS_NN    33024
#define LDS_POS   33088
#define POSSTRIDE 768
#define LDS_RED   33088
#define LDS_TOT   (33088 + 8*768)

__device__ inline unsigned short f2bf(float x) {           // RNE, pre-kernel
    unsigned int u = __float_as_uint(x);
    unsigned int r = (u + 0x7FFFu + ((u >> 16) & 1u)) >> 16;
    return (unsigned short)r;
}

__device__ inline unsigned short f2bf_fast(float x) {      // native RNE convert
    __hip_bfloat16 b = __float2bfloat16(x);
    return *reinterpret_cast<unsigned short*>(&b);
}

__global__ void kpconv_pre(const float* __restrict__ s_feats,
                           const float* __restrict__ weights,
                           unsigned short* __restrict__ xbf,
                           unsigned short* __restrict__ wfrag) {
    int t = blockIdx.x * 256 + threadIdx.x;
    if (t < 800000) {                       // 3.2M elems / 4
        int i = t * 4;
        float4 v = *(const float4*)(s_feats + i);
        ushort4 o;
        o.x = f2bf(v.x); o.y = f2bf(v.y); o.z = f2bf(v.z); o.w = f2bf(v.w);
        *(ushort4*)(xbf + i) = o;
    } else {
        int tw = t - 800000;
        if (tw < 8192) {                    // 128 frags x 64 lanes, 16 B each
            const int f = tw >> 6, l = tw & 63;
            const int m = l & 15, h = l >> 4;
            const int dt = f >> 5, kh = (f >> 4) & 1, jj = f & 15;
            const int d = dt * 16 + m;
            const int pcb = (kh * 16 + jj) * 32 + 8 * h;
            ushort4 o0, o1;
            unsigned short* op0 = (unsigned short*)&o0;
            unsigned short* op1 = (unsigned short*)&o1;
            #pragma unroll
            for (int e = 0; e < 8; ++e) {
                const int pc = pcb + e;
                const int p = pc & 15, c = pc >> 4;
                const float wv = (p < 15) ? weights[(p * 64 + c) * 64 + d] : 0.0f;
                if (e < 4) op0[e] = f2bf(wv); else op1[e - 4] = f2bf(wv);
            }
            *(ushort4*)(wfrag + tw * 8) = o0;
            *(ushort4*)(wfrag + tw * 8 + 4) = o1;
        }
    }
}

__global__ __launch_bounds__(512, 8) void kpconv_main(
    const float* __restrict__ qpts, const float* __restrict__ spts,
    const int* __restrict__ nbr, const float* __restrict__ kpts,
    const unsigned short* __restrict__ xbf, const unsigned short* __restrict__ wfrag,
    float* __restrict__ out)
{
    __shared__ __attribute__((aligned(128))) unsigned char lds[LDS_TOT];
    const int tid = threadIdx.x;
    const int w = tid >> 6;       // 0..7
    const int l = tid & 63;
    const int h = l >> 4;         // 0..3
    const int m = l & 15;
    const int qbase = blockIdx.x * 16;

    const int pm = (m < 15) ? m : 14;
    const float kx = kpts[pm * 3 + 0], ky = kpts[pm * 3 + 1], kz = kpts[pm * 3 + 2];

    unsigned char* xw = lds + w * XSLICE;
    unsigned char* posb = lds + LDS_POS + w * POSSTRIDE;   // xy[64] then z[64]

    // ============ LOAD-ISSUE REGION: all gathers in flight together ========
    // ---- ONE coalesced load: lane l = (query l>>5, neighbor l&31)
    const int* nbase = nbr + (qbase + 2 * w) * 32;
    const int sBoth = nbase[l];

    // ---- staging row indices: direct imm-offset loads (nbr row is L1-hot)
    const int voff = l >> 3;
    int sidx[2][4];
    #pragma unroll
    for (int i = 0; i < 2; ++i)
        #pragma unroll
        for (int g = 0; g < 4; ++g)
            sidx[i][g] = nbase[32 * i + 8 * g + voff];

    // ---- position gather (depends only on sBoth)
    const float2 pxy = *(const float2*)(spts + (size_t)sBoth * 3);
    const float pz = spts[(size_t)sBoth * 3 + 2];

    // ---- xbf gathers, both queries upfront: instr (i,g) reads 8 FULL rows.
    //      Issued while the spts gather is still in flight (no fence between).
    int4 xv[2][4];
    #pragma unroll
    for (int i = 0; i < 2; ++i)
        #pragma unroll
        for (int g = 0; g < 4; ++g)
            xv[i][g] = *(const int4*)(xbf + (size_t)sidx[i][g] * 64 + (l & 7) * 8);
    // =======================================================================

    // ---- stage SoA {xy}[l], {z}[l]: counted vmcnt waits only for spts loads;
    //      the 8 xv gathers remain outstanding.
    *(float2*)(posb + l * 8) = pxy;
    *(float*)(posb + 512 + l * 4) = pz;

    // ---- x-tile write bases: column slot = c ^ ((c>>5)&1); c = 8*(l&7)+e
    const int eb = (l >> 2) & 1;
    unsigned char* wb2base = xw + (l & 7) * 512 + (l >> 3) * 2;
    unsigned char* wb2E = wb2base + eb * 64;
    unsigned char* wb2O = wb2base + (eb ^ 1) * 64;
    const int xb2 = (l & 3) << 4;
    // read bases: ct<2 -> slot m; ct>=2 -> slot m^1 (bit0 column flip)
    unsigned char* rb3a = xw + m * 64;
    unsigned char* rb3b = xw + (m ^ 1) * 64;
    const int rxb = (h ^ (m >> 3)) << 4;

    uint2 pk0[4];                 // deferred wtd pack for query 0 (aliases x buf)

    #pragma unroll
    for (int i = 0; i < 2; ++i) {
        const int ql = 2 * w + i;
        const int q = qbase + ql;

        // ---- neighbor_num: ballot per instr-group, bit-fold (row = 8-lane octet)
        int nn = 0;
        #pragma unroll
        for (int g = 0; g < 4; ++g) {
            const int4 v = xv[i][g];
            unsigned long long b = __ballot((v.x | v.y | v.z | v.w) != 0);
            b |= b >> 4; b |= b >> 2; b |= b >> 1;
            nn += __popcll(b & 0x0101010101010101ULL);
        }
        if (nn < 1) nn = 1;
        if (l == 0) *(int*)(lds + LDS_NN + ql * 4) = nn;

        // ---- scatter-stage x^T (32-bank spread); q1 overwrites after q0 use
        #pragma unroll
        for (int g = 0; g < 4; ++g) {
            const unsigned short* u8 = (const unsigned short*)&xv[i][g];
            const int gofs = (g << 4) ^ xb2;
            unsigned char* wgE = wb2E + gofs;
            unsigned char* wgO = wb2O + gofs;
            #pragma unroll
            for (int t = 0; t < 4; ++t) {
                *(unsigned short*)(wgE + t * 128) = u8[2 * t];
                *(unsigned short*)(wgO + t * 128) = u8[2 * t + 1];
            }
        }

        // ---- A-frag: lane holds w[k=8h+j][p=m]; direct-difference form
        const float qx = qpts[q * 3 + 0], qy = qpts[q * 3 + 1], qz = qpts[q * 3 + 2];
        const float bx = qx + kx, by = qy + ky, bz = qz + kz;
        float wv[8];
        #pragma unroll
        for (int j = 0; j < 8; ++j) {
            const float2 sxy = *(const float2*)(posb + (32 * i + j) * 8 + h * 64);
            const float sz = *(const float*)(posb + 512 + (32 * i + j) * 4 + h * 32);
            const float dx = sxy.x - bx, dy = sxy.y - by, dz = sz - bz;
            const float d2 = __builtin_fmaf(dx, dx,
                             __builtin_fmaf(dy, dy, dz * dz));
            const float s = __builtin_amdgcn_sqrtf(d2);
            wv[j] = fmaxf(__builtin_fmaf(s, -0.5f, 1.0f), 0.0f);
        }
        union { unsigned int d[4]; short8 s8; } au;
        const bool pad = (m == 15);          // p=15 is the zero pad
        #pragma unroll
        for (int jp = 0; jp < 4; ++jp) {
            const unsigned int pk = (unsigned int)f2bf_fast(wv[2 * jp]) |
                                    ((unsigned int)f2bf_fast(wv[2 * jp + 1]) << 16);
            au.d[jp] = pad ? 0u : pk;
        }

        // ---- B-frags + step-3 MFMAs (b128 reads, 8 lanes/quad balanced)
        f32x4 c3[4];
        #pragma unroll
        for (int ct = 0; ct < 4; ++ct) {
            const unsigned char* rb = (ct < 2) ? rb3a : rb3b;
            short8 b3 = *(const short8*)(rb + ct * 1024 + (rxb ^ ((ct & 1) << 5)));
            f32x4 z = {0.f, 0.f, 0.f, 0.f};
            c3[ct] = __builtin_amdgcn_mfma_f32_16x16x32_bf16(au.s8, b3, z, 0, 0, 0);
        }

        // ---- pack wtd (pc' = c*16+p; lane holds p=4h+r, c=16ct+m)
        #pragma unroll
        for (int ct = 0; ct < 4; ++ct) {
            uint2 pkv;
            pkv.x = (unsigned int)f2bf_fast(c3[ct][0]) | ((unsigned int)f2bf_fast(c3[ct][1]) << 16);
            pkv.y = (unsigned int)f2bf_fast(c3[ct][2]) | ((unsigned int)f2bf_fast(c3[ct][3]) << 16);
            if (i == 0) {
                pk0[ct] = pkv;               // row 2w aliases x buf: defer
            } else {
                *(uint2*)(lds + ql * QSTRIDE + (ct * 16 + m) * 32 + h * 8) = pkv;
            }
        }
    }

    // ---- flush query 0's deferred wtd row
    #pragma unroll
    for (int ct = 0; ct < 4; ++ct)
        *(uint2*)(lds + (2 * w) * QSTRIDE + (ct * 16 + m) * 32 + h * 8) = pk0[ct];

    __syncthreads();

    // ---- phase 4 (split-K): wave w -> d-tile (w&3), k-half (w>>2)
    const int dt = w & 3, kh = w >> 2;
    const int d = dt * 16 + m;
    f32x4 acc0 = {0.f, 0.f, 0.f, 0.f}, acc1 = {0.f, 0.f, 0.f, 0.f};
    const unsigned char* abase = lds + m * QSTRIDE + 16 * h;
    const unsigned short* bbase = wfrag + (size_t)((dt * 2 + kh) * 16) * 512 + l * 8;
    const int k0 = kh * 16;
    #pragma unroll
    for (int j = 0; j < 8; ++j) {
        short8 a4a = *(const short8*)(abase + (k0 + j) * 64);
        short8 b4a = *(const short8*)(bbase + j * 512);
        acc0 = __builtin_amdgcn_mfma_f32_16x16x32_bf16(a4a, b4a, acc0, 0, 0, 0);
        short8 a4b = *(const short8*)(abase + (k0 + 8 + j) * 64);
        short8 b4b = *(const short8*)(bbase + (8 + j) * 512);
        acc1 = __builtin_amdgcn_mfma_f32_16x16x32_bf16(a4b, b4b, acc1, 0, 0, 0);
    }

    if (kh == 1) {
        f32x4 acc = acc0 + acc1;
        *(f32x4*)(lds + LDS_RED + dt * 1024 + l * 16) = acc;
    }
    __syncthreads();
    if (kh == 0) {
        f32x4 part = *(const f32x4*)(lds + LDS_RED + dt * 1024 + l * 16);
        #pragma unroll
        for (int r = 0; r < 4; ++r) {
            const int qr = 4 * h + r;
            const int nn = *(const int*)(lds + LDS_NN + qr * 4);
            out[(size_t)(qbase + qr) * 64 + d] =
                (acc0[r] + acc1[r] + part[r]) * (1.0f / (float)nn);
        }
    }
}

extern "C" void kernel_launch(void* const* d_in, const int* in_sizes, int n_in,
                              void* d_out, int out_size, void* d_ws, size_t ws_size,
                              hipStream_t stream) {
    const float* s_feats = (const float*)d_in[0];
    const float* q_points = (const float*)d_in[1];
    const float* s_points = (const float*)d_in[2];
    const int* nbr = (const int*)d_in[3];
    const float* kpts = (const float*)d_in[4];
    const float* wts = (const float*)d_in[5];
    float* out = (float*)d_out;

    unsigned short* xbf = (unsigned short*)d_ws;
    unsigned short* wfrag = (unsigned short*)((char*)d_ws + WT_BYTE_OFF);

    // prekernel: 800000 threads for xbf + 8192 for wfrag -> 3157 blocks
    hipLaunchKernelGGL(kpconv_pre, dim3(3157), dim3(256), 0, stream,
                       s_feats, wts, xbf, wfrag);
    hipLaunchKernelGGL(kpconv_main, dim3(3125), dim3(512), 0, stream,
                       q_points, s_points, nbr, kpts, xbf, wfrag, out);
}